// Round 2
// baseline (179.325 us; speedup 1.0000x reference)
//
#include <hip/hip_runtime.h>

#define D_ 160
#define H_ 192
#define W_ 160
#define HW_ (H_*W_)
#define V_ (D_*H_*W_)
#define NTOT (2*V_)

#define TW 32
#define TH 16
#define DC 20
#define NCHUNK (D_/DC)    // 8
#define RH 24             // TH + 8 halo
#define TWP 33            // ws stride pad (33%8==1 -> uniform quad-banks)
#define NBLOCKS (5*12*NCHUNK*2)   // 960

// 16B zero page for boundary/out-of-range DMA sources (L2-resident; keeps
// per-wave global_load_lds issue count uniform so counted vmcnt is sound).
__device__ __align__(64) float zpad_g[4] = {0.f, 0.f, 0.f, 0.f};

// 16B global->LDS DMA. LDS dest = wave-uniform base + lane*16 (m97/m104).
#define GLD16(gp, lp) \
  __builtin_amdgcn_global_load_lds( \
      (const __attribute__((address_space(1))) unsigned int*)(const void*)(gp), \
      (__attribute__((address_space(3))) unsigned int*)(void*)(lp), 16, 0, 0)

// RTNE f32x2 -> packed bf16x2 and back (validated R5/R6/R8: absmax 0.0).
__device__ inline unsigned pack_bf2(float a, float b) {
  unsigned ua = __float_as_uint(a), ub = __float_as_uint(b);
  ua += 0x7fffu + ((ua >> 16) & 1u);
  ub += 0x7fffu + ((ub >> 16) & 1u);
  return (ua & 0xffff0000u) | (ub >> 16);
}
__device__ inline float2 unpack_bf2(unsigned u) {
  return make_float2(__uint_as_float(u & 0xffff0000u),
                     __uint_as_float(u << 16));
}

// ---------------------------------------------------------------------------
// Fused separable 9x9x9 box filter + NCC.
// R9: raw s_barrier + COUNTED vmcnt (T3/T4) -> 111 -> 87 us dispatch.
// R10: kill the 2-round occupancy tail. 960 blocks at 3/CU = 768 slots ->
// two rounds, 62.5% utilization (matches VALUBusy 40% w/ no pipe saturated).
// ws double-buffer was redundant (the mid barrier already covers the WAR,
// the end barrier the RAW) -> single-buffer ws, LDS 47104 -> 31232 B ->
// __launch_bounds__(256,4): 4 blocks/CU, all 960 blocks resident, one round.
// VGPR demand is 76 (counter) -- far under the 128 cap, no spill risk.
// Per step t (ring slot u = t mod 9 static via 9-unroll):
//   issue stage(t) -> sIJ[t&1]           (every wave exactly 2 GLD16)
//   C(t): H-dir 9-sums of ws + bf16 D-ring + emit
//   s_waitcnt vmcnt(2); s_barrier        (drains stage(t-1); stage(t) flies)
//   B(t): reads sIJ[(t-1)&1] -> W-dir 9-sums -> ws
//   s_waitcnt lgkmcnt(0); s_barrier      (ws visible to C(t+1); sIJ safe to DMA)
// Barriers only needed t<29; t=30..35 are no-ops (ring-flush padding).
// ---------------------------------------------------------------------------
__global__ __launch_bounds__(256, 4) void ncc_fused(const float* __restrict__ I,
                                                    const float* __restrict__ J,
                                                    float* __restrict__ bsum) {
  __shared__ float4 sIJ[2][480];       // [buf][ I quads 0..239 | J quads 240..479 ]
  __shared__ float4 ws4[RH][TWP];      // W-sums f0-3  12672 B
  __shared__ float  ws1[RH][TWP];      // W-sums f4     3168 B

  const int tid = threadIdx.x;
  const int w0 = blockIdx.x * TW;               // 5
  const int h0 = blockIdx.y * TH;               // 12
  const int c0 = (blockIdx.z % NCHUNK) * DC;    // 8 chunks
  const int batch = blockIdx.z / NCHUNK;        // 2

  const float* Ib = I + (size_t)batch * V_;
  const float* Jb = J + (size_t)batch * V_;
  const float* zp = zpad_g;

  // Staging chunks g0=tid, g1=tid+256 of 480. chunk g: arr=g/240, rem=g%240,
  // row r=rem/10 (h=h0-4+r), quad q=rem%10 (col=w0-4+4q, quad-aligned).
  const int g0 = tid, g1 = tid + 256;
  const int a0 = g0 / 240, rem0 = g0 % 240;
  const int r0 = rem0 / 10, q0 = rem0 % 10;
  const int h0g = h0 - 4 + r0, c0g = w0 - 4 + 4 * q0;
  const bool ok0 = ((unsigned)h0g < (unsigned)H_) && ((unsigned)c0g < (unsigned)W_);
  const float* gb0 = (a0 ? Jb : Ib) + (ok0 ? ((size_t)h0g * W_ + c0g) : 0);

  const int a1 = (g1 / 240) & 1, rem1 = g1 % 240;
  const int r1 = rem1 / 10, q1 = rem1 % 10;
  const int h1g = h0 - 4 + r1, c1g = w0 - 4 + 4 * q1;
  const bool okd1 = ((unsigned)h1g < (unsigned)H_) && ((unsigned)c1g < (unsigned)W_);
  const float* gb1 = (a1 ? Jb : Ib) + (okd1 ? ((size_t)h1g * W_ + c1g) : 0);

  // Wave-uniform LDS byte bases for the two DMA issues.
  const int wv  = tid >> 6;
  const int wb0 = wv * 1024;           // chunks [wv*64, wv*64+64)
  const int wb1 = 4096 + wv * 1024;    // chunks [256+wv*64, ...)

  // B mapping (tid < 192): 24 rows x 8 runs of 4
  const int br = tid >> 3;
  const int brun = tid & 7;
  const int bc = brun * 4;

  // C mapping: col tx, output rows hb, hb+1
  const int tx = tid & 31;
  const int hb = (tid >> 5) * 2;

  unsigned ring[5][9];
  float sum0[5], sum1[5];
#pragma unroll
  for (int f = 0; f < 5; ++f) {
    sum0[f] = 0.f; sum1[f] = 0.f;
#pragma unroll
    for (int k = 0; k < 9; ++k) ring[f][k] = 0u;
  }

  float local = 0.f;

#pragma unroll 1
  for (int tb = 0; tb < 36; tb += 9) {
#pragma unroll
    for (int u = 0; u < 9; ++u) {
      const int t = tb + u;          // 0..35; phases self-guard (30..35 idle)

      // ---- stage: slice s = c0-4+t -> sIJ[t&1]; EVERY wave issues 2 DMAs ----
      if (t < DC + 8) {
        const int s = c0 - 4 + t;
        const bool sin = (unsigned)s < (unsigned)D_;
        const size_t so = sin ? (size_t)s * HW_ : 0;
        char* lbase = (char*)&sIJ[t & 1][0];
        const float* A0 = (sin && ok0) ? (gb0 + so) : zp;
        GLD16(A0, lbase + wb0);
        if (g1 < 480) {                // lane-masked (wave 3 partial exec);
          const float* A1 = (sin && okd1) ? (gb1 + so) : zp;  // still 1 issue/wave
          GLD16(A1, lbase + wb1);
        }
      }

      // ---- C: H-dir 9-sums of ws + bf16 D-ring (static slot u) ----
      if (t >= 2 && t < DC + 10) {
        float v0 = 0.f, v1 = 0.f, v2 = 0.f, v3 = 0.f, v4 = 0.f;
        float4 k4; float k1v;
#pragma unroll
        for (int k = 0; k < 9; ++k) {
          const float4 a4 = ws4[hb + k][tx];
          const float  a1f = ws1[hb + k][tx];
          if (k == 0) { k4 = a4; k1v = a1f; }
          v0 += a4.x; v1 += a4.y; v2 += a4.z; v3 += a4.w; v4 += a1f;
        }
        const float4 t4 = ws4[hb + 9][tx];
        const float  t1 = ws1[hb + 9][tx];
        float hv0[5], hv1[5];
        hv0[0] = v0; hv0[1] = v1; hv0[2] = v2; hv0[3] = v3; hv0[4] = v4;
        hv1[0] = v0 + t4.x - k4.x;
        hv1[1] = v1 + t4.y - k4.y;
        hv1[2] = v2 + t4.z - k4.z;
        hv1[3] = v3 + t4.w - k4.w;
        hv1[4] = v4 + t1   - k1v;

#pragma unroll
        for (int f = 0; f < 5; ++f) {
          const float2 old = unpack_bf2(ring[f][u]);
          sum0[f] += hv0[f] - old.x;
          sum1[f] += hv1[f] - old.y;
          ring[f][u] = pack_bf2(hv0[f], hv1[f]);
        }

        if (t >= 10) {
          const float inv = 1.f / 729.f;
          const float cx0 = sum0[4] - sum0[0] * sum0[1] * inv;
          const float iv0 = sum0[2] - sum0[0] * sum0[0] * inv;
          const float jv0 = sum0[3] - sum0[1] * sum0[1] * inv;
          local += cx0 * cx0 * __builtin_amdgcn_rcpf(iv0 * jv0 + 1e-5f);
          const float cx1 = sum1[4] - sum1[0] * sum1[1] * inv;
          const float iv1 = sum1[2] - sum1[0] * sum1[0] * inv;
          const float jv1 = sum1[3] - sum1[1] * sum1[1] * inv;
          local += cx1 * cx1 * __builtin_amdgcn_rcpf(iv1 * jv1 + 1e-5f);
        }
      }

      // ---- mid barrier: drain stage(t-1) ONLY; stage(t) stays in flight.
      //      Also covers the ws WAR (C reads above vs B writes below).
      //      Not needed past t=28 (last B). ----
      if (t < DC + 9) {
        if (t < DC + 8) {
          asm volatile("s_waitcnt vmcnt(2)" ::: "memory");
        } else {
          asm volatile("s_waitcnt vmcnt(0)" ::: "memory");   // tail drain (t==28)
        }
        __builtin_amdgcn_s_barrier();
      }

      // ---- B: W-dir 9-sums from sIJ[(t-1)&1] (6x ds_read_b128) -> ws ----
      if (t >= 1 && t < DC + 9 && tid < 192) {
        const float4* SI = &sIJ[(t + 1) & 1][br * 10 + brun];
        const float4* SJ = SI + 240;
        const float4 A0 = SI[0], A1 = SI[1], A2 = SI[2];
        const float4 B0 = SJ[0], B1 = SJ[1], B2 = SJ[2];
        const float ai[12] = {A0.x,A0.y,A0.z,A0.w, A1.x,A1.y,A1.z,A1.w,
                              A2.x,A2.y,A2.z,A2.w};
        const float aj[12] = {B0.x,B0.y,B0.z,B0.w, B1.x,B1.y,B1.z,B1.w,
                              B2.x,B2.y,B2.z,B2.w};
        float4* W4 = ws4[br];
        float*  W1 = ws1[br];
        float s0 = 0.f, s1 = 0.f, s2 = 0.f, s3 = 0.f, s4 = 0.f;
#pragma unroll
        for (int k = 0; k < 9; ++k) {
          const float a = ai[k], b = aj[k];
          s0 += a; s1 += b; s2 += a * a; s3 += b * b; s4 += a * b;
        }
        W4[bc] = make_float4(s0, s1, s2, s3);
        W1[bc] = s4;
#pragma unroll
        for (int m = 1; m < 4; ++m) {
          const float ea = ai[8 + m], eb = aj[8 + m];
          const float la = ai[m - 1], lb = aj[m - 1];
          s0 += ea - la;
          s1 += eb - lb;
          s2 += ea * ea - la * la;
          s3 += eb * eb - lb * lb;
          s4 += ea * eb - la * lb;
          W4[bc + m] = make_float4(s0, s1, s2, s3);
          W1[bc + m] = s4;
        }
      }

      // ---- end barrier: B's ws writes visible to C(t+1); B's sIJ reads done
      //      before stage(t+1)'s DMA lands. Not needed past t=28. ----
      if (t < DC + 9) {
        asm volatile("s_waitcnt lgkmcnt(0)" ::: "memory");
        __builtin_amdgcn_s_barrier();
      }
    }
  }

  // ---- block reduction (reuse ws4 space) -> per-block partial ----
  __syncthreads();   // C(29)'s ws reads are consumed before anyone overwrites
  float* red = (float*)&ws4[0][0];
  red[tid] = local;
  __syncthreads();
  for (int s2 = 128; s2 > 0; s2 >>= 1) {
    if (tid < s2) red[tid] += red[tid + s2];
    __syncthreads();
  }
  if (tid == 0) {
    const int bid = (blockIdx.z * 12 + blockIdx.y) * 5 + blockIdx.x;
    bsum[bid] = red[0];
  }
}

__global__ __launch_bounds__(256) void finalize_k(const float* __restrict__ bsum,
                                                  float* __restrict__ out) {
  __shared__ double red[256];
  double d = 0.0;
  for (int i = threadIdx.x; i < NBLOCKS; i += 256) d += (double)bsum[i];
  red[threadIdx.x] = d;
  __syncthreads();
  for (int s = 128; s > 0; s >>= 1) {
    if (threadIdx.x < s) red[threadIdx.x] += red[threadIdx.x + s];
    __syncthreads();
  }
  if (threadIdx.x == 0) out[0] = (float)(-red[0] / (double)NTOT);
}

extern "C" void kernel_launch(void* const* d_in, const int* in_sizes, int n_in,
                              void* d_out, int out_size, void* d_ws, size_t ws_size,
                              hipStream_t stream) {
  const float* I = (const float*)d_in[0];   // y_true
  const float* J = (const float*)d_in[1];   // y_pred
  float* out = (float*)d_out;
  float* bsum = (float*)d_ws;               // 960 floats

  dim3 grid(W_ / TW, H_ / TH, NCHUNK * 2);  // 5 x 12 x 16 = 960 blocks
  ncc_fused<<<grid, 256, 0, stream>>>(I, J, bsum);
  finalize_k<<<1, 256, 0, stream>>>(bsum, out);
}

// Round 3
// 163.363 us; speedup vs baseline: 1.0977x; 1.0977x over previous
//
#include <hip/hip_runtime.h>

#define D_ 160
#define H_ 192
#define W_ 160
#define HW_ (H_*W_)
#define V_ (D_*H_*W_)
#define NTOT (2*V_)

#define TW 32
#define TH 16
#define DC 20
#define NCHUNK (D_/DC)    // 8
#define RH 24             // TH + 8 halo
#define TWP 33            // ws stride pad (33%8==1 -> uniform quad-banks)
#define NBLOCKS (5*12*NCHUNK*2)   // 960

// 16B zero page for boundary/out-of-range DMA sources (L2-resident; keeps
// per-wave global_load_lds issue count uniform so counted vmcnt is sound).
__device__ __align__(64) float zpad_g[4] = {0.f, 0.f, 0.f, 0.f};

// 16B global->LDS DMA. LDS dest = wave-uniform base + lane*16 (m97/m104).
#define GLD16(gp, lp) \
  __builtin_amdgcn_global_load_lds( \
      (const __attribute__((address_space(1))) unsigned int*)(const void*)(gp), \
      (__attribute__((address_space(3))) unsigned int*)(void*)(lp), 16, 0, 0)

// RTNE f32x2 -> packed bf16x2 and back (validated R5/R6/R8: absmax 0.0).
__device__ inline unsigned pack_bf2(float a, float b) {
  unsigned ua = __float_as_uint(a), ub = __float_as_uint(b);
  ua += 0x7fffu + ((ua >> 16) & 1u);
  ub += 0x7fffu + ((ub >> 16) & 1u);
  return (ua & 0xffff0000u) | (ub >> 16);
}
__device__ inline float2 unpack_bf2(unsigned u) {
  return make_float2(__uint_as_float(u & 0xffff0000u),
                     __uint_as_float(u << 16));
}

// ---------------------------------------------------------------------------
// Fused separable 9x9x9 box filter + NCC.
// R9:  counted vmcnt + raw barriers -> 111 -> 87 us.
// R10: FAILED -- __launch_bounds__(256,4) forced a 128-reg GUARANTEE -> spill
//      (WRITE_SIZE 30KB -> 97MB). Lesson: actual demand (76) is <=128 already;
//      the HW schedules 4 blocks/CU on its own if LDS <= 40960B. Keep (256,3).
// R11: two stacked fixes:
//  (a) LDS 47104 -> 38880 B (triple staging + SINGLE ws) => 4 blocks/CU
//      residency with the relaxed reg cap -> 960 blocks in ONE round (no tail).
//  (b) staging prefetch depth 2 (triple buffer, vmcnt(4)): each slice gets ~2
//      full steps of compute to land instead of ~1 (the residual per-step
//      stall: 4640 cyc wall vs ~1800 busy was marginally-hidden DMA latency).
// Pipeline (slice indices relative to chunk, u = t mod 9, t mod 3 = u mod 3
// static under the 9-unroll):
//   stage(t):  slice t -> sIJ[t%3]          t in [0,28)
//   C(t):      consumes ws = W-sums of slice t-3   t in [3,31), emit t>=11
//   mid-bar:   vmcnt(4|2|0) + s_barrier     t in [2,30)  (drains slice t-2;
//              stage(t),stage(t-1) stay in flight; also covers ws WAR)
//   B(t):      sIJ[(t-2)%3] -> W-sums of slice t-2 -> ws   t in [2,30)
//   end-bar:   lgkmcnt(0) + s_barrier       t in [2,30)  (ws RAW to C(t+1);
//              sIJ[(t+1)%3] readers done before stage(t+1) overwrites)
// Steps 31..35: ring-flush idle padding (no barriers, compiler prunes).
// ---------------------------------------------------------------------------
__global__ __launch_bounds__(256, 3) void ncc_fused(const float* __restrict__ I,
                                                    const float* __restrict__ J,
                                                    float* __restrict__ bsum) {
  __shared__ float4 sIJ[3][480];       // 23040 B  [buf][ I 0..239 | J 240..479 ]
  __shared__ float4 ws4[RH][TWP];      // 12672 B  W-sums f0-3
  __shared__ float  ws1[RH][TWP];      //  3168 B  W-sums f4
                                       // total 38880 B -> 4 blocks/CU

  const int tid = threadIdx.x;
  const int w0 = blockIdx.x * TW;               // 5
  const int h0 = blockIdx.y * TH;               // 12
  const int c0 = (blockIdx.z % NCHUNK) * DC;    // 8 chunks
  const int batch = blockIdx.z / NCHUNK;        // 2

  const float* Ib = I + (size_t)batch * V_;
  const float* Jb = J + (size_t)batch * V_;
  const float* zp = zpad_g;

  // Staging chunks g0=tid, g1=tid+256 of 480. chunk g: arr=g/240, rem=g%240,
  // row r=rem/10 (h=h0-4+r), quad q=rem%10 (col=w0-4+4q, quad-aligned).
  const int g0 = tid, g1 = tid + 256;
  const int a0 = g0 / 240, rem0 = g0 % 240;
  const int r0 = rem0 / 10, q0 = rem0 % 10;
  const int h0g = h0 - 4 + r0, c0g = w0 - 4 + 4 * q0;
  const bool ok0 = ((unsigned)h0g < (unsigned)H_) && ((unsigned)c0g < (unsigned)W_);
  const float* gb0 = (a0 ? Jb : Ib) + (ok0 ? ((size_t)h0g * W_ + c0g) : 0);

  const int a1 = (g1 / 240) & 1, rem1 = g1 % 240;
  const int r1 = rem1 / 10, q1 = rem1 % 10;
  const int h1g = h0 - 4 + r1, c1g = w0 - 4 + 4 * q1;
  const bool okd1 = ((unsigned)h1g < (unsigned)H_) && ((unsigned)c1g < (unsigned)W_);
  const float* gb1 = (a1 ? Jb : Ib) + (okd1 ? ((size_t)h1g * W_ + c1g) : 0);

  // Wave-uniform LDS byte bases for the two DMA issues.
  const int wv  = tid >> 6;
  const int wb0 = wv * 1024;           // chunks [wv*64, wv*64+64)
  const int wb1 = 4096 + wv * 1024;    // chunks [256+wv*64, ...)

  // B mapping (tid < 192): 24 rows x 8 runs of 4
  const int br = tid >> 3;
  const int brun = tid & 7;
  const int bc = brun * 4;

  // C mapping: col tx, output rows hb, hb+1
  const int tx = tid & 31;
  const int hb = (tid >> 5) * 2;

  unsigned ring[5][9];
  float sum0[5], sum1[5];
#pragma unroll
  for (int f = 0; f < 5; ++f) {
    sum0[f] = 0.f; sum1[f] = 0.f;
#pragma unroll
    for (int k = 0; k < 9; ++k) ring[f][k] = 0u;
  }

  float local = 0.f;

#pragma unroll 1
  for (int tb = 0; tb < 36; tb += 9) {
#pragma unroll
    for (int u = 0; u < 9; ++u) {
      const int t = tb + u;          // 0..35; phases self-guard (31..35 idle)

      // ---- stage: slice s = c0-4+t -> sIJ[t%3]; EVERY wave issues 2 DMAs ----
      if (t < DC + 8) {
        const int s = c0 - 4 + t;
        const bool sin = (unsigned)s < (unsigned)D_;
        const size_t so = sin ? (size_t)s * HW_ : 0;
        char* lbase = (char*)&sIJ[u % 3][0];   // t%3 == u%3 (tb multiple of 9)
        const float* A0 = (sin && ok0) ? (gb0 + so) : zp;
        GLD16(A0, lbase + wb0);
        if (g1 < 480) {                // lane-masked (wave 3 partial exec);
          const float* A1 = (sin && okd1) ? (gb1 + so) : zp;  // still 1 issue/wave
          GLD16(A1, lbase + wb1);
        }
      }

      // ---- C: H-dir 9-sums of ws (= slice t-3) + bf16 D-ring (slot u) ----
      if (t >= 3 && t < DC + 11) {
        float v0 = 0.f, v1 = 0.f, v2 = 0.f, v3 = 0.f, v4 = 0.f;
        float4 k4; float k1v;
#pragma unroll
        for (int k = 0; k < 9; ++k) {
          const float4 a4 = ws4[hb + k][tx];
          const float  a1f = ws1[hb + k][tx];
          if (k == 0) { k4 = a4; k1v = a1f; }
          v0 += a4.x; v1 += a4.y; v2 += a4.z; v3 += a4.w; v4 += a1f;
        }
        const float4 t4 = ws4[hb + 9][tx];
        const float  t1 = ws1[hb + 9][tx];
        float hv0[5], hv1[5];
        hv0[0] = v0; hv0[1] = v1; hv0[2] = v2; hv0[3] = v3; hv0[4] = v4;
        hv1[0] = v0 + t4.x - k4.x;
        hv1[1] = v1 + t4.y - k4.y;
        hv1[2] = v2 + t4.z - k4.z;
        hv1[3] = v3 + t4.w - k4.w;
        hv1[4] = v4 + t1   - k1v;

#pragma unroll
        for (int f = 0; f < 5; ++f) {
          const float2 old = unpack_bf2(ring[f][u]);
          sum0[f] += hv0[f] - old.x;
          sum1[f] += hv1[f] - old.y;
          ring[f][u] = pack_bf2(hv0[f], hv1[f]);
        }

        if (t >= 11) {
          const float inv = 1.f / 729.f;
          const float cx0 = sum0[4] - sum0[0] * sum0[1] * inv;
          const float iv0 = sum0[2] - sum0[0] * sum0[0] * inv;
          const float jv0 = sum0[3] - sum0[1] * sum0[1] * inv;
          local += cx0 * cx0 * __builtin_amdgcn_rcpf(iv0 * jv0 + 1e-5f);
          const float cx1 = sum1[4] - sum1[0] * sum1[1] * inv;
          const float iv1 = sum1[2] - sum1[0] * sum1[0] * inv;
          const float jv1 = sum1[3] - sum1[1] * sum1[1] * inv;
          local += cx1 * cx1 * __builtin_amdgcn_rcpf(iv1 * jv1 + 1e-5f);
        }
      }

      // ---- mid barrier: drain slice t-2 (stage(t), stage(t-1) stay in
      //      flight). Also covers the ws WAR (C reads above, B writes below).
      if (t >= 2 && t < DC + 10) {
        if (t < DC + 8) {
          asm volatile("s_waitcnt vmcnt(4)" ::: "memory");
        } else if (t == DC + 8) {
          asm volatile("s_waitcnt vmcnt(2)" ::: "memory");
        } else {
          asm volatile("s_waitcnt vmcnt(0)" ::: "memory");
        }
        __builtin_amdgcn_s_barrier();
      }

      // ---- B: W-dir 9-sums of slice t-2 from sIJ[(t-2)%3] -> ws ----
      if (t >= 2 && t < DC + 10 && tid < 192) {
        const float4* SI = &sIJ[(u + 1) % 3][br * 10 + brun];  // (t-2)%3
        const float4* SJ = SI + 240;
        const float4 A0 = SI[0], A1 = SI[1], A2 = SI[2];
        const float4 B0 = SJ[0], B1 = SJ[1], B2 = SJ[2];
        const float ai[12] = {A0.x,A0.y,A0.z,A0.w, A1.x,A1.y,A1.z,A1.w,
                              A2.x,A2.y,A2.z,A2.w};
        const float aj[12] = {B0.x,B0.y,B0.z,B0.w, B1.x,B1.y,B1.z,B1.w,
                              B2.x,B2.y,B2.z,B2.w};
        float4* W4 = ws4[br];
        float*  W1 = ws1[br];
        float s0 = 0.f, s1 = 0.f, s2 = 0.f, s3 = 0.f, s4 = 0.f;
#pragma unroll
        for (int k = 0; k < 9; ++k) {
          const float a = ai[k], b = aj[k];
          s0 += a; s1 += b; s2 += a * a; s3 += b * b; s4 += a * b;
        }
        W4[bc] = make_float4(s0, s1, s2, s3);
        W1[bc] = s4;
#pragma unroll
        for (int m = 1; m < 4; ++m) {
          const float ea = ai[8 + m], eb = aj[8 + m];
          const float la = ai[m - 1], lb = aj[m - 1];
          s0 += ea - la;
          s1 += eb - lb;
          s2 += ea * ea - la * la;
          s3 += eb * eb - lb * lb;
          s4 += ea * eb - la * lb;
          W4[bc + m] = make_float4(s0, s1, s2, s3);
          W1[bc + m] = s4;
        }
      }

      // ---- end barrier: ws RAW to C(t+1); sIJ[(t+1)%3] readers (B(t)) done
      //      before stage(t+1) overwrites it.
      if (t >= 2 && t < DC + 10) {
        asm volatile("s_waitcnt lgkmcnt(0)" ::: "memory");
        __builtin_amdgcn_s_barrier();
      }
    }
  }

  // ---- block reduction (reuse ws4 space) -> per-block partial ----
  __syncthreads();   // C(30)'s ws reads consumed before the space is reused
  float* red = (float*)&ws4[0][0];
  red[tid] = local;
  __syncthreads();
  for (int s2 = 128; s2 > 0; s2 >>= 1) {
    if (tid < s2) red[tid] += red[tid + s2];
    __syncthreads();
  }
  if (tid == 0) {
    const int bid = (blockIdx.z * 12 + blockIdx.y) * 5 + blockIdx.x;
    bsum[bid] = red[0];
  }
}

__global__ __launch_bounds__(256) void finalize_k(const float* __restrict__ bsum,
                                                  float* __restrict__ out) {
  __shared__ double red[256];
  double d = 0.0;
  for (int i = threadIdx.x; i < NBLOCKS; i += 256) d += (double)bsum[i];
  red[threadIdx.x] = d;
  __syncthreads();
  for (int s = 128; s > 0; s >>= 1) {
    if (threadIdx.x < s) red[threadIdx.x] += red[threadIdx.x + s];
    __syncthreads();
  }
  if (threadIdx.x == 0) out[0] = (float)(-red[0] / (double)NTOT);
}

extern "C" void kernel_launch(void* const* d_in, const int* in_sizes, int n_in,
                              void* d_out, int out_size, void* d_ws, size_t ws_size,
                              hipStream_t stream) {
  const float* I = (const float*)d_in[0];   // y_true
  const float* J = (const float*)d_in[1];   // y_pred
  float* out = (float*)d_out;
  float* bsum = (float*)d_ws;               // 960 floats

  dim3 grid(W_ / TW, H_ / TH, NCHUNK * 2);  // 5 x 12 x 16 = 960 blocks
  ncc_fused<<<grid, 256, 0, stream>>>(I, J, bsum);
  finalize_k<<<1, 256, 0, stream>>>(bsum, out);
}